// Round 9
// baseline (166.950 us; speedup 1.0000x reference)
//
#include <hip/hip_runtime.h>

typedef short short8 __attribute__((ext_vector_type(8)));
typedef float f32x4 __attribute__((ext_vector_type(4)));

#define H 128
#define NB 8            // real batch rows per block (grid*NB MUST equal 4096!)
#define TSTEPS 64
#define PRED 32
#define XSTRIDE 260

// R9 geometry: 512 blocks x 256 thr (4 waves) = 2 independent barrier domains
// per CU (8 waves/CU, 2/SIMD). Each wave owns TWO 16-col tiles (jj0=w*32+ln,
// jj1=jj0+16) sharing ONE set of A-fragments. Rows: 16-row MFMA tile with 8
// real rows at D-regs {0,1} (LDS rows {0,1,4,5,8,9,12,13}); garbage rows are
// zeroed once, never rewritten, never read back as real data.
// R8 lesson: grid*NB must equal B — the 512x16 launch was OOB (core dump).
// R6 lesson: never demand occupancy beyond the register footprint (spills).
// R3 lesson: no numerics changes on the recurrence datapath.

static __device__ __forceinline__ unsigned short bf16_rne(float f) {
  unsigned u = __builtin_bit_cast(unsigned, f);
  u += 0x7fffu + ((u >> 16) & 1u);
  return (unsigned short)(u >> 16);
}
static __device__ __forceinline__ float bf16_f(unsigned short s) {
  unsigned u = ((unsigned)s) << 16;
  return __builtin_bit_cast(float, u);
}
// R2's tanh (verified end-to-end). Do NOT swap for raw v_exp/v_rcp — that
// variant cost 43x accuracy over the 96-step recurrence (R3 post-mortem).
static __device__ __forceinline__ float tanh_fast(float v) {
  v = fminf(9.0f, fmaxf(-9.0f, v));
  float e = __expf(2.0f * v);
  return __fdividef(e - 1.0f, e + 1.0f);
}

static __device__ __forceinline__ void split_frag(const f32x4& a, const f32x4& b,
                                                  short8& hi, short8& lo) {
  #pragma unroll
  for (int e = 0; e < 4; ++e) {
    unsigned short h1 = bf16_rne(a[e]);
    hi[e] = (short)h1;
    lo[e] = (short)bf16_rne(a[e] - bf16_f(h1));
    unsigned short h2 = bf16_rne(b[e]);
    hi[e + 4] = (short)h2;
    lo[e + 4] = (short)bf16_rne(b[e] - bf16_f(h2));
  }
}

__global__ __launch_bounds__(256, 2) void traj_kernel(
    const float* __restrict__ x,
    const float* __restrict__ eWih, const float* __restrict__ eWhh,
    const float* __restrict__ ebih, const float* __restrict__ ebhh,
    const float* __restrict__ dWih, const float* __restrict__ dWhh,
    const float* __restrict__ dbih, const float* __restrict__ dbhh,
    const float* __restrict__ fcW, const float* __restrict__ fcb,
    float* __restrict__ out)
{
  __shared__ __align__(16) float x_lds[16 * XSTRIDE];          // 16.6 KB
  __shared__ __align__(16) short h_hi0[16 * H], h_lo0[16 * H];
  __shared__ __align__(16) short h_hi1[16 * H], h_lo1[16 * H]; // 16 KB
  __shared__ float inp_lds[16][4];

  const int tid = threadIdx.x;
  const int lane = tid & 63;
  const int w = tid >> 6;          // wave 0..3 -> one 32-col super-tile
  const int l4 = lane >> 4;
  const int ln = lane & 15;
  const int r0 = blockIdx.x * NB;  // 512 blocks x 8 rows = 4096 ✓
  const int jj0 = w * 32 + ln;     // this lane's two hidden columns
  const int jj1 = jj0 + 16;

  // ---- stage x: 16 LDS rows (real rows + finite duplicates) ----
  #pragma unroll
  for (int s = 0; s < 12; ++s) {
    int flat = tid + s * 256;      // = ldsrow*192 + rem
    int r = flat / 192;
    int rem = flat - r * 192;
    int t = rem / 3;
    int i = rem - t * 3;
    int g = (r >> 2) * 2 + (r & 1);          // LDS row -> real batch row
    x_lds[r * XSTRIDE + t * 4 + i] = x[(size_t)(r0 + g) * 192 + rem];
  }
  // ---- zero BOTH h buffers (garbage rows must stay finite forever) ----
  #pragma unroll
  for (int s = 0; s < 8; ++s) {
    h_hi0[tid + s * 256] = 0; h_hi1[tid + s * 256] = 0;
    h_lo0[tid + s * 256] = 0; h_lo1[tid + s * 256] = 0;
  }

  // ---- encoder weights (rows jj0, jj1 of eWhh), split hi/lo ----
  short8 whi[2][4], wlo[2][4];
  #pragma unroll
  for (int ct = 0; ct < 2; ++ct) {
    const int j = ct ? jj1 : jj0;
    #pragma unroll
    for (int kt = 0; kt < 4; ++kt) {
      const float* p = eWhh + j * H + kt * 32 + l4 * 8;
      split_frag(*(const f32x4*)p, *(const f32x4*)(p + 4), whi[ct][kt], wlo[ct][kt]);
    }
  }
  float bias0 = ebih[jj0] + ebhh[jj0];
  float bias1 = ebih[jj1] + ebhh[jj1];
  float wi0[3], wi1[3];
  #pragma unroll
  for (int i = 0; i < 3; ++i) { wi0[i] = eWih[jj0 * 3 + i]; wi1[i] = eWih[jj1 * 3 + i]; }

  // ---- loop-invariant LDS offsets (real rows = D-regs {0,1}) ----
  int roff[4];
  #pragma unroll
  for (int kt = 0; kt < 4; ++kt)
    roff[kt] = ln * H + ((((kt << 2) + l4) ^ ln) << 3);   // swizzled A-frag
  int wo0[2], wo1[2], xb[2];
  #pragma unroll
  for (int reg = 0; reg < 2; ++reg) {
    const int r = l4 * 4 + reg;                           // real LDS row
    wo0[reg] = r * H + (((jj0 >> 3) ^ r) << 3) + (jj0 & 7);
    wo1[reg] = r * H + (((jj1 >> 3) ^ r) << 3) + (jj1 & 7);
    xb[reg] = r * XSTRIDE;
  }

  auto load_frags = [&](const short* __restrict__ hh, const short* __restrict__ hl,
                        short8* ah, short8* al) {
    #pragma unroll
    for (int kt = 0; kt < 4; ++kt) {
      ah[kt] = *(const short8*)&hh[roff[kt]];
      al[kt] = *(const short8*)&hl[roff[kt]];
    }
  };
  // One RNN step for this wave's two 16-col tiles. A-frags shared by both.
  auto rnn_core = [&](const short8* ah, const short8* al, f32x4 a0, f32x4 a1,
                      short* __restrict__ wh, short* __restrict__ wl) {
    f32x4 b0 = {0.f, 0.f, 0.f, 0.f}, b1 = {0.f, 0.f, 0.f, 0.f};
    f32x4 c0 = {0.f, 0.f, 0.f, 0.f}, c1 = {0.f, 0.f, 0.f, 0.f};
    #pragma unroll
    for (int kt = 0; kt < 4; ++kt) {   // 6 independent 4-deep MFMA chains
      a0 = __builtin_amdgcn_mfma_f32_16x16x32_bf16(ah[kt], whi[0][kt], a0, 0, 0, 0);
      a1 = __builtin_amdgcn_mfma_f32_16x16x32_bf16(ah[kt], whi[1][kt], a1, 0, 0, 0);
      b0 = __builtin_amdgcn_mfma_f32_16x16x32_bf16(ah[kt], wlo[0][kt], b0, 0, 0, 0);
      b1 = __builtin_amdgcn_mfma_f32_16x16x32_bf16(ah[kt], wlo[1][kt], b1, 0, 0, 0);
      c0 = __builtin_amdgcn_mfma_f32_16x16x32_bf16(al[kt], whi[0][kt], c0, 0, 0, 0);
      c1 = __builtin_amdgcn_mfma_f32_16x16x32_bf16(al[kt], whi[1][kt], c1, 0, 0, 0);
    }
    #pragma unroll
    for (int reg = 0; reg < 2; ++reg) {  // real rows only
      float v0 = tanh_fast(a0[reg] + b0[reg] + c0[reg]);
      float v1 = tanh_fast(a1[reg] + b1[reg] + c1[reg]);
      unsigned short p0 = bf16_rne(v0);
      unsigned short p1 = bf16_rne(v1);
      wh[wo0[reg]] = (short)p0;
      wl[wo0[reg]] = (short)bf16_rne(v0 - bf16_f(p0));
      wh[wo1[reg]] = (short)p1;
      wl[wo1[reg]] = (short)bf16_rne(v1 - bf16_f(p1));
    }
  };

  __syncthreads();

  // ======================= encoder: 64 steps, unrolled x2 =======================
  for (int t = 0; t < TSTEPS; t += 2) {
    {
      short8 ah[4], al[4];
      load_frags(h_hi0, h_lo0, ah, al);
      f32x4 a0 = {0.f, 0.f, bias0, bias0}, a1 = {0.f, 0.f, bias1, bias1};
      #pragma unroll
      for (int reg = 0; reg < 2; ++reg) {
        const f32x4 xv = *(const f32x4*)&x_lds[xb[reg] + t * 4];
        a0[reg] = bias0 + wi0[0] * xv[0] + wi0[1] * xv[1] + wi0[2] * xv[2];
        a1[reg] = bias1 + wi1[0] * xv[0] + wi1[1] * xv[1] + wi1[2] * xv[2];
      }
      rnn_core(ah, al, a0, a1, h_hi1, h_lo1);
    }
    __syncthreads();
    {
      short8 ah[4], al[4];
      load_frags(h_hi1, h_lo1, ah, al);
      f32x4 a0 = {0.f, 0.f, bias0, bias0}, a1 = {0.f, 0.f, bias1, bias1};
      #pragma unroll
      for (int reg = 0; reg < 2; ++reg) {
        const f32x4 xv = *(const f32x4*)&x_lds[xb[reg] + (t + 1) * 4];
        a0[reg] = bias0 + wi0[0] * xv[0] + wi0[1] * xv[1] + wi0[2] * xv[2];
        a1[reg] = bias1 + wi1[0] * xv[0] + wi1[1] * xv[1] + wi1[2] * xv[2];
      }
      rnn_core(ah, al, a0, a1, h_hi0, h_lo0);
    }
    __syncthreads();
  }
  // h_enc now in h_hi0/h_lo0.

  // ======================= decoder setup =======================
  #pragma unroll
  for (int ct = 0; ct < 2; ++ct) {
    const int j = ct ? jj1 : jj0;
    #pragma unroll
    for (int kt = 0; kt < 4; ++kt) {
      const float* p = dWhh + j * H + kt * 32 + l4 * 8;
      split_frag(*(const f32x4*)p, *(const f32x4*)(p + 4), whi[ct][kt], wlo[ct][kt]);
    }
  }
  bias0 = dbih[jj0] + dbhh[jj0];
  bias1 = dbih[jj1] + dbhh[jj1];
  #pragma unroll
  for (int i = 0; i < 3; ++i) { wi0[i] = dWih[jj0 * 3 + i]; wi1[i] = dWih[jj1 * 3 + i]; }

  // fc head as MFMA B-fragments: B[k][n=o] = fcW[o][k], lanes ln>=3 zero.
  short8 fhi[4];
  #pragma unroll
  for (int kt = 0; kt < 4; ++kt) {
    f32x4 a = {0.f, 0.f, 0.f, 0.f}, b = {0.f, 0.f, 0.f, 0.f};
    if (ln < 3) {
      const float* p = fcW + ln * H + kt * 32 + l4 * 8;
      a = *(const f32x4*)p;
      b = *(const f32x4*)(p + 4);
    }
    short8 hi;
    #pragma unroll
    for (int e = 0; e < 4; ++e) {
      hi[e] = (short)bf16_rne(a[e]);
      hi[e + 4] = (short)bf16_rne(b[e]);
    }
    fhi[kt] = hi;
  }
  const float fcbl = (ln < 3) ? fcb[ln] : 0.f;

  if (tid < 48) {                       // all 16 LDS rows (dups finite)
    int r = tid / 3, i = tid - 3 * (tid / 3);
    inp_lds[r][i] = x_lds[r * XSTRIDE + 63 * 4 + i];   // dec_in0 = x[:, -1, :]
  }
  __syncthreads();

  // ---- decoder step 0 (raw dWhh + real input) ----
  {
    short8 ah[4], al[4];
    load_frags(h_hi0, h_lo0, ah, al);
    f32x4 a0 = {0.f, 0.f, bias0, bias0}, a1 = {0.f, 0.f, bias1, bias1};
    #pragma unroll
    for (int reg = 0; reg < 2; ++reg) {
      const int r = l4 * 4 + reg;       // real LDS row
      a0[reg] = bias0 + wi0[0] * inp_lds[r][0] + wi0[1] * inp_lds[r][1]
                      + wi0[2] * inp_lds[r][2];
      a1[reg] = bias1 + wi1[0] * inp_lds[r][0] + wi1[1] * inp_lds[r][1]
                      + wi1[2] * inp_lds[r][2];
    }
    rnn_core(ah, al, a0, a1, h_hi1, h_lo1);
  }
  __syncthreads();

  // ---- fold feedback: W' = dWhh + dWih@fcW ; bias' = bias + dWih@fcb ----
  #pragma unroll
  for (int ct = 0; ct < 2; ++ct) {
    const int j = ct ? jj1 : jj0;
    const float* wip = ct ? wi1 : wi0;
    #pragma unroll
    for (int kt = 0; kt < 4; ++kt) {
      const int kb = kt * 32 + l4 * 8;
      f32x4 a = *(const f32x4*)(dWhh + j * H + kb);
      f32x4 b = *(const f32x4*)(dWhh + j * H + kb + 4);
      #pragma unroll
      for (int o = 0; o < 3; ++o) {
        const f32x4 fa = *(const f32x4*)(fcW + o * H + kb);
        const f32x4 fb = *(const f32x4*)(fcW + o * H + kb + 4);
        #pragma unroll
        for (int e = 0; e < 4; ++e) {
          a[e] += wip[o] * fa[e];
          b[e] += wip[o] * fb[e];
        }
      }
      split_frag(a, b, whi[ct][kt], wlo[ct][kt]);
    }
  }
  const float biasp0 = bias0 + wi0[0] * fcb[0] + wi0[1] * fcb[1] + wi0[2] * fcb[2];
  const float biasp1 = bias1 + wi1[0] * fcb[0] + wi1[1] * fcb[1] + wi1[2] * fcb[2];
  const f32x4 accd0 = {biasp0, biasp0, biasp0, biasp0};
  const f32x4 accd1 = {biasp1, biasp1, biasp1, biasp1};

  // ======================= decoder steps 1..31: 1 barrier/step =======================
  const short* rdh = h_hi1; const short* rdl = h_lo1;
  short* wrh = h_hi0;       short* wrl = h_lo0;
  for (int s = 1; s < PRED; ++s) {
    short8 ah[4], al[4];
    load_frags(rdh, rdl, ah, al);
    rnn_core(ah, al, accd0, accd1, wrh, wrl);
    // pred[s-1] = fcW·h[s-1] + fcb via MFMA on one rotating wave (off-path)
    if (w == (s & 3)) {
      f32x4 p0 = {0.f, 0.f, 0.f, 0.f};
      f32x4 p1 = {0.f, 0.f, 0.f, 0.f};
      #pragma unroll
      for (int kt = 0; kt < 4; ++kt) {
        p0 = __builtin_amdgcn_mfma_f32_16x16x32_bf16(ah[kt], fhi[kt], p0, 0, 0, 0);
        p1 = __builtin_amdgcn_mfma_f32_16x16x32_bf16(al[kt], fhi[kt], p1, 0, 0, 0);
      }
      if (ln < 3) {
        #pragma unroll
        for (int reg = 0; reg < 2; ++reg)   // real rows: batch l4*2+reg
          out[((size_t)(r0 + l4 * 2 + reg) * PRED + (s - 1)) * 3 + ln] =
              p0[reg] + p1[reg] + fcbl;
      }
    }
    __syncthreads();
    const short* th = rdh; rdh = wrh; wrh = (short*)th;
    const short* tl = rdl; rdl = wrl; wrl = (short*)tl;
  }
  // ---- drain: pred[31] from final h ----
  if (w == 0) {
    short8 ah[4], al[4];
    load_frags(rdh, rdl, ah, al);
    f32x4 p0 = {0.f, 0.f, 0.f, 0.f};
    f32x4 p1 = {0.f, 0.f, 0.f, 0.f};
    #pragma unroll
    for (int kt = 0; kt < 4; ++kt) {
      p0 = __builtin_amdgcn_mfma_f32_16x16x32_bf16(ah[kt], fhi[kt], p0, 0, 0, 0);
      p1 = __builtin_amdgcn_mfma_f32_16x16x32_bf16(al[kt], fhi[kt], p1, 0, 0, 0);
    }
    if (ln < 3) {
      #pragma unroll
      for (int reg = 0; reg < 2; ++reg)
        out[((size_t)(r0 + l4 * 2 + reg) * PRED + (PRED - 1)) * 3 + ln] =
            p0[reg] + p1[reg] + fcbl;
    }
  }
}

extern "C" void kernel_launch(void* const* d_in, const int* in_sizes, int n_in,
                              void* d_out, int out_size, void* d_ws, size_t ws_size,
                              hipStream_t stream) {
  (void)in_sizes; (void)n_in; (void)out_size; (void)d_ws; (void)ws_size;
  const float* x    = (const float*)d_in[0];
  const float* eWih = (const float*)d_in[1];
  const float* eWhh = (const float*)d_in[2];
  const float* ebih = (const float*)d_in[3];
  const float* ebhh = (const float*)d_in[4];
  const float* dWih = (const float*)d_in[5];
  const float* dWhh = (const float*)d_in[6];
  const float* dbih = (const float*)d_in[7];
  const float* dbhh = (const float*)d_in[8];
  const float* fcW  = (const float*)d_in[9];
  const float* fcb  = (const float*)d_in[10];
  float* out = (float*)d_out;
  traj_kernel<<<dim3(512), dim3(256), 0, stream>>>(   // 512*NB(8) = 4096 rows
      x, eWih, eWhh, ebih, ebhh, dWih, dWhh, dbih, dbhh, fcW, fcb, out);
}

// Round 10
// 166.404 us; speedup vs baseline: 1.0033x; 1.0033x over previous
//
#include <hip/hip_runtime.h>

typedef short short8 __attribute__((ext_vector_type(8)));
typedef float f32x4 __attribute__((ext_vector_type(4)));

#define H 128
#define NB 16           // real batch rows per block (grid*NB == 4096)
#define TSTEPS 64
#define PRED 32

// R10 geometry: 256 blocks x 256 thr (4 waves), 1 block/CU, NB=16 (all rows
// real). Each wave owns 32 cols as ADJACENT pairs: lane ln -> cols
// jj0=w*32+2*ln and jj1=jj0+1. A-fragments (full h) are read once per wave:
// 32 ds_read_b128/CU-step (half of R7's 64 — R7 was LDS-pipe-bound).
// Adjacent cols pack the hi/lo epilogue writes into single b32 stores.
// x comes from GLOBAL per-lane loads, prefetched one step ahead (off the
// LDS pipe, latency hidden, summation order identical).
// R9 lesson: extra barrier domains don't pay; duplicated MFMA does cost.
// R8 lesson: grid*NB must equal B. R6 lesson: occupancy demands must fit the
// register footprint. R3 lesson: no numerics changes on the recurrence.

static __device__ __forceinline__ unsigned short bf16_rne(float f) {
  unsigned u = __builtin_bit_cast(unsigned, f);
  u += 0x7fffu + ((u >> 16) & 1u);
  return (unsigned short)(u >> 16);
}
static __device__ __forceinline__ float bf16_f(unsigned short s) {
  unsigned u = ((unsigned)s) << 16;
  return __builtin_bit_cast(float, u);
}
// R2's tanh (verified end-to-end). Do NOT swap for raw v_exp/v_rcp — that
// variant cost 43x accuracy over the 96-step recurrence (R3 post-mortem).
static __device__ __forceinline__ float tanh_fast(float v) {
  v = fminf(9.0f, fmaxf(-9.0f, v));
  float e = __expf(2.0f * v);
  return __fdividef(e - 1.0f, e + 1.0f);
}

static __device__ __forceinline__ void split_frag(const f32x4& a, const f32x4& b,
                                                  short8& hi, short8& lo) {
  #pragma unroll
  for (int e = 0; e < 4; ++e) {
    unsigned short h1 = bf16_rne(a[e]);
    hi[e] = (short)h1;
    lo[e] = (short)bf16_rne(a[e] - bf16_f(h1));
    unsigned short h2 = bf16_rne(b[e]);
    hi[e + 4] = (short)h2;
    lo[e + 4] = (short)bf16_rne(b[e] - bf16_f(h2));
  }
}

__global__ __launch_bounds__(256, 1) void traj_kernel(
    const float* __restrict__ x,
    const float* __restrict__ eWih, const float* __restrict__ eWhh,
    const float* __restrict__ ebih, const float* __restrict__ ebhh,
    const float* __restrict__ dWih, const float* __restrict__ dWhh,
    const float* __restrict__ dbih, const float* __restrict__ dbhh,
    const float* __restrict__ fcW, const float* __restrict__ fcb,
    float* __restrict__ out)
{
  __shared__ __align__(16) short h_hi0[NB * H], h_lo0[NB * H];
  __shared__ __align__(16) short h_hi1[NB * H], h_lo1[NB * H]; // 16 KB total

  const int tid = threadIdx.x;
  const int lane = tid & 63;
  const int w = tid >> 6;          // wave 0..3 -> one 32-col super-tile
  const int l4 = lane >> 4;
  const int ln = lane & 15;
  const int r0 = blockIdx.x * NB;  // 256 blocks x 16 rows = 4096 ✓
  const int jj0 = w * 32 + 2 * ln; // adjacent column pair
  const int jj1 = jj0 + 1;

  // ---- zero h buffer 0 (h0 = 0); every step fully rewrites the dst buffer ----
  #pragma unroll
  for (int s = 0; s < 8; ++s) {
    h_hi0[tid + s * 256] = 0;
    h_lo0[tid + s * 256] = 0;
  }

  // ---- encoder weights (rows jj0, jj1 of eWhh), split hi/lo ----
  short8 whi[2][4], wlo[2][4];
  #pragma unroll
  for (int ct = 0; ct < 2; ++ct) {
    const int j = ct ? jj1 : jj0;
    #pragma unroll
    for (int kt = 0; kt < 4; ++kt) {
      const float* p = eWhh + j * H + kt * 32 + l4 * 8;
      split_frag(*(const f32x4*)p, *(const f32x4*)(p + 4), whi[ct][kt], wlo[ct][kt]);
    }
  }
  float bias0 = ebih[jj0] + ebhh[jj0];
  float bias1 = ebih[jj1] + ebhh[jj1];
  float wi0[3], wi1[3];
  #pragma unroll
  for (int i = 0; i < 3; ++i) { wi0[i] = eWih[jj0 * 3 + i]; wi1[i] = eWih[jj1 * 3 + i]; }

  // ---- loop-invariant offsets ----
  int roff[4];
  #pragma unroll
  for (int kt = 0; kt < 4; ++kt)
    roff[kt] = ln * H + ((((kt << 2) + l4) ^ ln) << 3);   // swizzled A-frag
  int wob[4];                       // packed b32 write: cols (jj0, jj1) adjacent
  const float* xrow[4];
  #pragma unroll
  for (int reg = 0; reg < 4; ++reg) {
    const int r = l4 * 4 + reg;
    wob[reg] = r * H + (((jj0 >> 3) ^ r) << 3) + (jj0 & 7);  // even -> 4B aligned
    xrow[reg] = x + (size_t)(r0 + r) * 192;
  }

  auto load_frags = [&](const short* __restrict__ hh, const short* __restrict__ hl,
                        short8* ah, short8* al) {
    #pragma unroll
    for (int kt = 0; kt < 4; ++kt) {
      ah[kt] = *(const short8*)&hh[roff[kt]];
      al[kt] = *(const short8*)&hl[roff[kt]];
    }
  };
  // One RNN step for this wave's two adjacent-col tiles. A-frags shared.
  auto rnn_core = [&](const short8* ah, const short8* al, f32x4 a0, f32x4 a1,
                      short* __restrict__ wh, short* __restrict__ wl) {
    f32x4 b0 = {0.f, 0.f, 0.f, 0.f}, b1 = {0.f, 0.f, 0.f, 0.f};
    f32x4 c0 = {0.f, 0.f, 0.f, 0.f}, c1 = {0.f, 0.f, 0.f, 0.f};
    #pragma unroll
    for (int kt = 0; kt < 4; ++kt) {   // 6 independent 4-deep MFMA chains
      a0 = __builtin_amdgcn_mfma_f32_16x16x32_bf16(ah[kt], whi[0][kt], a0, 0, 0, 0);
      a1 = __builtin_amdgcn_mfma_f32_16x16x32_bf16(ah[kt], whi[1][kt], a1, 0, 0, 0);
      b0 = __builtin_amdgcn_mfma_f32_16x16x32_bf16(ah[kt], wlo[0][kt], b0, 0, 0, 0);
      b1 = __builtin_amdgcn_mfma_f32_16x16x32_bf16(ah[kt], wlo[1][kt], b1, 0, 0, 0);
      c0 = __builtin_amdgcn_mfma_f32_16x16x32_bf16(al[kt], whi[0][kt], c0, 0, 0, 0);
      c1 = __builtin_amdgcn_mfma_f32_16x16x32_bf16(al[kt], whi[1][kt], c1, 0, 0, 0);
    }
    #pragma unroll
    for (int reg = 0; reg < 4; ++reg) {
      float v0 = tanh_fast(a0[reg] + b0[reg] + c0[reg]);
      float v1 = tanh_fast(a1[reg] + b1[reg] + c1[reg]);
      unsigned short p0 = bf16_rne(v0);
      unsigned short p1 = bf16_rne(v1);
      unsigned short l0 = bf16_rne(v0 - bf16_f(p0));
      unsigned short l1 = bf16_rne(v1 - bf16_f(p1));
      *(unsigned*)&wh[wob[reg]] = (unsigned)p0 | ((unsigned)p1 << 16);
      *(unsigned*)&wl[wob[reg]] = (unsigned)l0 | ((unsigned)l1 << 16);
    }
  };

  // ---- x prefetch pipeline (global, per-lane scalar loads) ----
  float xc[4][3], xn[4][3];
  #pragma unroll
  for (int reg = 0; reg < 4; ++reg)
    #pragma unroll
    for (int i = 0; i < 3; ++i) xc[reg][i] = xrow[reg][i];   // t = 0

  __syncthreads();

  // ======================= encoder: 64 steps, unrolled x2 =======================
  for (int t = 0; t < TSTEPS; t += 2) {
    {
      short8 ah[4], al[4];
      load_frags(h_hi0, h_lo0, ah, al);
      f32x4 a0, a1;
      #pragma unroll
      for (int reg = 0; reg < 4; ++reg) {
        a0[reg] = bias0 + wi0[0] * xc[reg][0] + wi0[1] * xc[reg][1] + wi0[2] * xc[reg][2];
        a1[reg] = bias1 + wi1[0] * xc[reg][0] + wi1[1] * xc[reg][1] + wi1[2] * xc[reg][2];
      }
      #pragma unroll
      for (int reg = 0; reg < 4; ++reg)    // prefetch t+1
        #pragma unroll
        for (int i = 0; i < 3; ++i) xn[reg][i] = xrow[reg][(t + 1) * 3 + i];
      rnn_core(ah, al, a0, a1, h_hi1, h_lo1);
      __syncthreads();
    }
    {
      short8 ah[4], al[4];
      load_frags(h_hi1, h_lo1, ah, al);
      f32x4 a0, a1;
      #pragma unroll
      for (int reg = 0; reg < 4; ++reg) {
        a0[reg] = bias0 + wi0[0] * xn[reg][0] + wi0[1] * xn[reg][1] + wi0[2] * xn[reg][2];
        a1[reg] = bias1 + wi1[0] * xn[reg][0] + wi1[1] * xn[reg][1] + wi1[2] * xn[reg][2];
      }
      const int tp = (t + 2 < TSTEPS) ? (t + 2) : (TSTEPS - 1);  // clamp (in-bounds dup)
      #pragma unroll
      for (int reg = 0; reg < 4; ++reg)    // prefetch t+2
        #pragma unroll
        for (int i = 0; i < 3; ++i) xc[reg][i] = xrow[reg][tp * 3 + i];
      rnn_core(ah, al, a0, a1, h_hi0, h_lo0);
      __syncthreads();
    }
  }
  // h_enc in h_hi0/h_lo0; xc now holds x[:, 63, :] == dec_in0. 

  // ======================= decoder setup =======================
  #pragma unroll
  for (int ct = 0; ct < 2; ++ct) {
    const int j = ct ? jj1 : jj0;
    #pragma unroll
    for (int kt = 0; kt < 4; ++kt) {
      const float* p = dWhh + j * H + kt * 32 + l4 * 8;
      split_frag(*(const f32x4*)p, *(const f32x4*)(p + 4), whi[ct][kt], wlo[ct][kt]);
    }
  }
  bias0 = dbih[jj0] + dbhh[jj0];
  bias1 = dbih[jj1] + dbhh[jj1];
  #pragma unroll
  for (int i = 0; i < 3; ++i) { wi0[i] = dWih[jj0 * 3 + i]; wi1[i] = dWih[jj1 * 3 + i]; }

  // fc head as MFMA B-fragments: B[k][n=o] = fcW[o][k], lanes ln>=3 zero.
  short8 fhi[4];
  #pragma unroll
  for (int kt = 0; kt < 4; ++kt) {
    f32x4 a = {0.f, 0.f, 0.f, 0.f}, b = {0.f, 0.f, 0.f, 0.f};
    if (ln < 3) {
      const float* p = fcW + ln * H + kt * 32 + l4 * 8;
      a = *(const f32x4*)p;
      b = *(const f32x4*)(p + 4);
    }
    short8 hi;
    #pragma unroll
    for (int e = 0; e < 4; ++e) {
      hi[e] = (short)bf16_rne(a[e]);
      hi[e + 4] = (short)bf16_rne(b[e]);
    }
    fhi[kt] = hi;
  }
  const float fcbl = (ln < 3) ? fcb[ln] : 0.f;

  // ---- decoder step 0 (raw dWhh + real input from xc) ----
  {
    short8 ah[4], al[4];
    load_frags(h_hi0, h_lo0, ah, al);
    f32x4 a0, a1;
    #pragma unroll
    for (int reg = 0; reg < 4; ++reg) {
      a0[reg] = bias0 + wi0[0] * xc[reg][0] + wi0[1] * xc[reg][1] + wi0[2] * xc[reg][2];
      a1[reg] = bias1 + wi1[0] * xc[reg][0] + wi1[1] * xc[reg][1] + wi1[2] * xc[reg][2];
    }
    rnn_core(ah, al, a0, a1, h_hi1, h_lo1);
  }
  __syncthreads();

  // ---- fold feedback: W' = dWhh + dWih@fcW ; bias' = bias + dWih@fcb ----
  #pragma unroll
  for (int ct = 0; ct < 2; ++ct) {
    const int j = ct ? jj1 : jj0;
    const float* wip = ct ? wi1 : wi0;
    #pragma unroll
    for (int kt = 0; kt < 4; ++kt) {
      const int kb = kt * 32 + l4 * 8;
      f32x4 a = *(const f32x4*)(dWhh + j * H + kb);
      f32x4 b = *(const f32x4*)(dWhh + j * H + kb + 4);
      #pragma unroll
      for (int o = 0; o < 3; ++o) {
        const f32x4 fa = *(const f32x4*)(fcW + o * H + kb);
        const f32x4 fb = *(const f32x4*)(fcW + o * H + kb + 4);
        #pragma unroll
        for (int e = 0; e < 4; ++e) {
          a[e] += wip[o] * fa[e];
          b[e] += wip[o] * fb[e];
        }
      }
      split_frag(a, b, whi[ct][kt], wlo[ct][kt]);
    }
  }
  const float biasp0 = bias0 + wi0[0] * fcb[0] + wi0[1] * fcb[1] + wi0[2] * fcb[2];
  const float biasp1 = bias1 + wi1[0] * fcb[0] + wi1[1] * fcb[1] + wi1[2] * fcb[2];
  const f32x4 accd0 = {biasp0, biasp0, biasp0, biasp0};
  const f32x4 accd1 = {biasp1, biasp1, biasp1, biasp1};

  // ======================= decoder steps 1..31: 1 barrier/step =======================
  const short* rdh = h_hi1; const short* rdl = h_lo1;
  short* wrh = h_hi0;       short* wrl = h_lo0;
  for (int s = 1; s < PRED; ++s) {
    short8 ah[4], al[4];
    load_frags(rdh, rdl, ah, al);
    rnn_core(ah, al, accd0, accd1, wrh, wrl);
    // pred[s-1] = fcW·h[s-1] + fcb via MFMA on one rotating wave (off-path)
    if (w == (s & 3)) {
      f32x4 p0 = {0.f, 0.f, 0.f, 0.f};
      f32x4 p1 = {0.f, 0.f, 0.f, 0.f};
      #pragma unroll
      for (int kt = 0; kt < 4; ++kt) {
        p0 = __builtin_amdgcn_mfma_f32_16x16x32_bf16(ah[kt], fhi[kt], p0, 0, 0, 0);
        p1 = __builtin_amdgcn_mfma_f32_16x16x32_bf16(al[kt], fhi[kt], p1, 0, 0, 0);
      }
      if (ln < 3) {
        #pragma unroll
        for (int reg = 0; reg < 4; ++reg)
          out[((size_t)(r0 + l4 * 4 + reg) * PRED + (s - 1)) * 3 + ln] =
              p0[reg] + p1[reg] + fcbl;
      }
    }
    __syncthreads();
    const short* th = rdh; rdh = wrh; wrh = (short*)th;
    const short* tl = rdl; rdl = wrl; wrl = (short*)tl;
  }
  // ---- drain: pred[31] from final h ----
  if (w == 0) {
    short8 ah[4], al[4];
    load_frags(rdh, rdl, ah, al);
    f32x4 p0 = {0.f, 0.f, 0.f, 0.f};
    f32x4 p1 = {0.f, 0.f, 0.f, 0.f};
    #pragma unroll
    for (int kt = 0; kt < 4; ++kt) {
      p0 = __builtin_amdgcn_mfma_f32_16x16x32_bf16(ah[kt], fhi[kt], p0, 0, 0, 0);
      p1 = __builtin_amdgcn_mfma_f32_16x16x32_bf16(al[kt], fhi[kt], p1, 0, 0, 0);
    }
    if (ln < 3) {
      #pragma unroll
      for (int reg = 0; reg < 4; ++reg)
        out[((size_t)(r0 + l4 * 4 + reg) * PRED + (PRED - 1)) * 3 + ln] =
            p0[reg] + p1[reg] + fcbl;
    }
  }
}

extern "C" void kernel_launch(void* const* d_in, const int* in_sizes, int n_in,
                              void* d_out, int out_size, void* d_ws, size_t ws_size,
                              hipStream_t stream) {
  (void)in_sizes; (void)n_in; (void)out_size; (void)d_ws; (void)ws_size;
  const float* x    = (const float*)d_in[0];
  const float* eWih = (const float*)d_in[1];
  const float* eWhh = (const float*)d_in[2];
  const float* ebih = (const float*)d_in[3];
  const float* ebhh = (const float*)d_in[4];
  const float* dWih = (const float*)d_in[5];
  const float* dWhh = (const float*)d_in[6];
  const float* dbih = (const float*)d_in[7];
  const float* dbhh = (const float*)d_in[8];
  const float* fcW  = (const float*)d_in[9];
  const float* fcb  = (const float*)d_in[10];
  float* out = (float*)d_out;
  traj_kernel<<<dim3(256), dim3(256), 0, stream>>>(   // 256*NB(16) = 4096 rows
      x, eWih, eWhh, ebih, ebhh, dWih, dWhh, dbih, dbhh, fcW, fcb, out);
}

// Round 11
// 136.903 us; speedup vs baseline: 1.2195x; 1.2155x over previous
//
#include <hip/hip_runtime.h>

typedef short short8 __attribute__((ext_vector_type(8)));
typedef float f32x4 __attribute__((ext_vector_type(4)));

#define H 128
#define NB 16           // real batch rows per block (grid*NB == 4096)
#define TSTEPS 64
#define PRED 32

// R11 = R7 geometry (256 blocks x 512 thr, 8 waves, 1 col-tile/wave, 1
// block/CU, 2 waves/SIMD — the measured TLP sweet spot) with:
//  * 2-term split: h·W ≈ Ah·Whi + Ah·Wlo (dropped Al·Whi). hl is a fresh
//    RNE-unbiased residual each step -> random-walk error ~1-2e-3 (vs R3's
//    biased-tanh failure mode). W's lo term KEPT (fixed error, coherent).
//    Halves LDS h traffic, cuts MFMA 1/3, shrinks epilogue.
//  * x via per-lane global prefetch (R10-proven, bit-identical summation).
// R10 lesson: don't trade TLP for traffic — chain latency dominates.
// R9 lesson: extra barrier domains don't pay; duplicated MFMA costs.
// R8 lesson: grid*NB must equal B. R6: occupancy demands must fit VGPRs.
// R3 lesson: no *biased* numerics changes on the recurrence.

static __device__ __forceinline__ unsigned short bf16_rne(float f) {
  unsigned u = __builtin_bit_cast(unsigned, f);
  u += 0x7fffu + ((u >> 16) & 1u);
  return (unsigned short)(u >> 16);
}
static __device__ __forceinline__ float bf16_f(unsigned short s) {
  unsigned u = ((unsigned)s) << 16;
  return __builtin_bit_cast(float, u);
}
// R2's tanh (verified end-to-end). Do NOT swap for raw v_exp/v_rcp — that
// variant cost 43x accuracy over the 96-step recurrence (R3 post-mortem).
static __device__ __forceinline__ float tanh_fast(float v) {
  v = fminf(9.0f, fmaxf(-9.0f, v));
  float e = __expf(2.0f * v);
  return __fdividef(e - 1.0f, e + 1.0f);
}

static __device__ __forceinline__ void split_frag(const f32x4& a, const f32x4& b,
                                                  short8& hi, short8& lo) {
  #pragma unroll
  for (int e = 0; e < 4; ++e) {
    unsigned short h1 = bf16_rne(a[e]);
    hi[e] = (short)h1;
    lo[e] = (short)bf16_rne(a[e] - bf16_f(h1));
    unsigned short h2 = bf16_rne(b[e]);
    hi[e + 4] = (short)h2;
    lo[e + 4] = (short)bf16_rne(b[e] - bf16_f(h2));
  }
}

__global__ __launch_bounds__(512, 2) void traj_kernel(
    const float* __restrict__ x,
    const float* __restrict__ eWih, const float* __restrict__ eWhh,
    const float* __restrict__ ebih, const float* __restrict__ ebhh,
    const float* __restrict__ dWih, const float* __restrict__ dWhh,
    const float* __restrict__ dbih, const float* __restrict__ dbhh,
    const float* __restrict__ fcW, const float* __restrict__ fcb,
    float* __restrict__ out)
{
  __shared__ __align__(16) short h_hi0[NB * H];   // 4 KB, XOR-swizzled
  __shared__ __align__(16) short h_hi1[NB * H];   // 4 KB

  const int tid = threadIdx.x;
  const int lane = tid & 63;
  const int w = tid >> 6;          // wave 0..7 -> 16-col tile
  const int l4 = lane >> 4;
  const int ln = lane & 15;
  const int r0 = blockIdx.x * NB;  // 256 blocks x 16 rows = 4096 ✓
  const int jj = w * 16 + ln;      // this lane's hidden column

  // ---- zero h buffer 0 (h0 = 0) ----
  #pragma unroll
  for (int s = 0; s < 4; ++s)
    h_hi0[tid + s * 512] = 0;

  // ---- encoder weights (row jj of eWhh), split hi/lo (both kept for W) ----
  short8 whi[4], wlo[4];
  #pragma unroll
  for (int kt = 0; kt < 4; ++kt) {
    const float* p = eWhh + jj * H + kt * 32 + l4 * 8;
    split_frag(*(const f32x4*)p, *(const f32x4*)(p + 4), whi[kt], wlo[kt]);
  }
  float bias = ebih[jj] + ebhh[jj];
  float wi[3];
  #pragma unroll
  for (int i = 0; i < 3; ++i) wi[i] = eWih[jj * 3 + i];

  // ---- loop-invariant offsets ----
  int roff[4];
  #pragma unroll
  for (int kt = 0; kt < 4; ++kt)
    roff[kt] = ln * H + ((((kt << 2) + l4) ^ ln) << 3);   // swizzled A-frag
  int wo[4];
  const float* xrow[4];
  #pragma unroll
  for (int reg = 0; reg < 4; ++reg) {
    const int r = l4 * 4 + reg;
    wo[reg] = r * H + (((jj >> 3) ^ r) << 3) + (jj & 7);  // swizzled write
    xrow[reg] = x + (size_t)(r0 + r) * 192;
  }

  auto load_frags = [&](const short* __restrict__ hh, short8* ah) {
    #pragma unroll
    for (int kt = 0; kt < 4; ++kt)
      ah[kt] = *(const short8*)&hh[roff[kt]];
  };
  // One RNN step: 2-term split (Ah·Whi + Ah·Wlo), hi-only h state.
  auto rnn_core = [&](const short8* ah, f32x4 acc0, short* __restrict__ wh) {
    f32x4 accb = {0.f, 0.f, 0.f, 0.f};
    #pragma unroll
    for (int kt = 0; kt < 4; ++kt) {   // 2 independent 4-deep MFMA chains
      acc0 = __builtin_amdgcn_mfma_f32_16x16x32_bf16(ah[kt], whi[kt], acc0, 0, 0, 0);
      accb = __builtin_amdgcn_mfma_f32_16x16x32_bf16(ah[kt], wlo[kt], accb, 0, 0, 0);
    }
    #pragma unroll
    for (int reg = 0; reg < 4; ++reg) {
      float v = tanh_fast(acc0[reg] + accb[reg]);
      wh[wo[reg]] = (short)bf16_rne(v);
    }
  };

  // ---- x prefetch pipeline (global, per-lane scalar loads) ----
  float xc[4][3], xn[4][3];
  #pragma unroll
  for (int reg = 0; reg < 4; ++reg)
    #pragma unroll
    for (int i = 0; i < 3; ++i) xc[reg][i] = xrow[reg][i];   // t = 0

  __syncthreads();

  // ======================= encoder: 64 steps, unrolled x2, 1 barrier/step ====
  for (int t = 0; t < TSTEPS; t += 2) {
    {
      short8 ah[4];
      load_frags(h_hi0, ah);
      f32x4 a;
      #pragma unroll
      for (int reg = 0; reg < 4; ++reg)
        a[reg] = bias + wi[0] * xc[reg][0] + wi[1] * xc[reg][1] + wi[2] * xc[reg][2];
      #pragma unroll
      for (int reg = 0; reg < 4; ++reg)    // prefetch t+1
        #pragma unroll
        for (int i = 0; i < 3; ++i) xn[reg][i] = xrow[reg][(t + 1) * 3 + i];
      rnn_core(ah, a, h_hi1);
      __syncthreads();
    }
    {
      short8 ah[4];
      load_frags(h_hi1, ah);
      f32x4 a;
      #pragma unroll
      for (int reg = 0; reg < 4; ++reg)
        a[reg] = bias + wi[0] * xn[reg][0] + wi[1] * xn[reg][1] + wi[2] * xn[reg][2];
      const int tp = (t + 2 < TSTEPS) ? (t + 2) : (TSTEPS - 1);  // clamp: xc ends = x[:,63,:]
      #pragma unroll
      for (int reg = 0; reg < 4; ++reg)    // prefetch t+2
        #pragma unroll
        for (int i = 0; i < 3; ++i) xc[reg][i] = xrow[reg][tp * 3 + i];
      rnn_core(ah, a, h_hi0);
      __syncthreads();
    }
  }
  // h_enc in h_hi0; xc holds x[:, 63, :] == dec_in0.

  // ======================= decoder setup =======================
  #pragma unroll
  for (int kt = 0; kt < 4; ++kt) {
    const float* p = dWhh + jj * H + kt * 32 + l4 * 8;
    split_frag(*(const f32x4*)p, *(const f32x4*)(p + 4), whi[kt], wlo[kt]);
  }
  bias = dbih[jj] + dbhh[jj];
  #pragma unroll
  for (int i = 0; i < 3; ++i) wi[i] = dWih[jj * 3 + i];

  // fc head as MFMA B-fragments: B[k][n=o] = fcW[o][k], lanes ln>=3 zero.
  short8 fhi[4];
  #pragma unroll
  for (int kt = 0; kt < 4; ++kt) {
    f32x4 a = {0.f, 0.f, 0.f, 0.f}, b = {0.f, 0.f, 0.f, 0.f};
    if (ln < 3) {
      const float* p = fcW + ln * H + kt * 32 + l4 * 8;
      a = *(const f32x4*)p;
      b = *(const f32x4*)(p + 4);
    }
    short8 hi;
    #pragma unroll
    for (int e = 0; e < 4; ++e) {
      hi[e] = (short)bf16_rne(a[e]);
      hi[e + 4] = (short)bf16_rne(b[e]);
    }
    fhi[kt] = hi;
  }
  const float fcbl = (ln < 3) ? fcb[ln] : 0.f;

  // ---- decoder step 0 (raw dWhh + real input from xc) ----
  {
    short8 ah[4];
    load_frags(h_hi0, ah);
    f32x4 a;
    #pragma unroll
    for (int reg = 0; reg < 4; ++reg)
      a[reg] = bias + wi[0] * xc[reg][0] + wi[1] * xc[reg][1] + wi[2] * xc[reg][2];
    rnn_core(ah, a, h_hi1);
  }
  __syncthreads();

  // ---- fold feedback: W' = dWhh + dWih@fcW ; bias' = bias + dWih@fcb ----
  #pragma unroll
  for (int kt = 0; kt < 4; ++kt) {
    const int kb = kt * 32 + l4 * 8;
    f32x4 a = *(const f32x4*)(dWhh + jj * H + kb);
    f32x4 b = *(const f32x4*)(dWhh + jj * H + kb + 4);
    #pragma unroll
    for (int o = 0; o < 3; ++o) {
      const f32x4 fa = *(const f32x4*)(fcW + o * H + kb);
      const f32x4 fb = *(const f32x4*)(fcW + o * H + kb + 4);
      #pragma unroll
      for (int e = 0; e < 4; ++e) {
        a[e] += wi[o] * fa[e];
        b[e] += wi[o] * fb[e];
      }
    }
    split_frag(a, b, whi[kt], wlo[kt]);
  }
  const float biasp = bias + wi[0] * fcb[0] + wi[1] * fcb[1] + wi[2] * fcb[2];
  const f32x4 accd = {biasp, biasp, biasp, biasp};

  // ======================= decoder steps 1..31: 1 barrier/step =======================
  const short* rdh = h_hi1;
  short* wrh = h_hi0;
  for (int s = 1; s < PRED; ++s) {
    short8 ah[4];
    load_frags(rdh, ah);
    rnn_core(ah, accd, wrh);
    // pred[s-1] = fcW·h[s-1] + fcb via MFMA on one rotating wave (off-path)
    if (w == (s & 7)) {
      f32x4 p0 = {0.f, 0.f, 0.f, 0.f};
      #pragma unroll
      for (int kt = 0; kt < 4; ++kt)
        p0 = __builtin_amdgcn_mfma_f32_16x16x32_bf16(ah[kt], fhi[kt], p0, 0, 0, 0);
      if (ln < 3) {
        #pragma unroll
        for (int reg = 0; reg < 4; ++reg)
          out[((size_t)(r0 + l4 * 4 + reg) * PRED + (s - 1)) * 3 + ln] =
              p0[reg] + fcbl;
      }
    }
    __syncthreads();
    const short* th = rdh; rdh = wrh; wrh = (short*)th;
  }
  // ---- drain: pred[31] from final h ----
  if (w == 0) {
    short8 ah[4];
    load_frags(rdh, ah);
    f32x4 p0 = {0.f, 0.f, 0.f, 0.f};
    #pragma unroll
    for (int kt = 0; kt < 4; ++kt)
      p0 = __builtin_amdgcn_mfma_f32_16x16x32_bf16(ah[kt], fhi[kt], p0, 0, 0, 0);
    if (ln < 3) {
      #pragma unroll
      for (int reg = 0; reg < 4; ++reg)
        out[((size_t)(r0 + l4 * 4 + reg) * PRED + (PRED - 1)) * 3 + ln] =
            p0[reg] + fcbl;
    }
  }
}

extern "C" void kernel_launch(void* const* d_in, const int* in_sizes, int n_in,
                              void* d_out, int out_size, void* d_ws, size_t ws_size,
                              hipStream_t stream) {
  (void)in_sizes; (void)n_in; (void)out_size; (void)d_ws; (void)ws_size;
  const float* x    = (const float*)d_in[0];
  const float* eWih = (const float*)d_in[1];
  const float* eWhh = (const float*)d_in[2];
  const float* ebih = (const float*)d_in[3];
  const float* ebhh = (const float*)d_in[4];
  const float* dWih = (const float*)d_in[5];
  const float* dWhh = (const float*)d_in[6];
  const float* dbih = (const float*)d_in[7];
  const float* dbhh = (const float*)d_in[8];
  const float* fcW  = (const float*)d_in[9];
  const float* fcb  = (const float*)d_in[10];
  float* out = (float*)d_out;
  traj_kernel<<<dim3(256), dim3(512), 0, stream>>>(   // 256*NB(16) = 4096 rows
      x, eWih, eWhh, ebih, ebhh, dWih, dWhh, dbih, dbhh, fcW, fcb, out);
}